// Round 5
// baseline (303.813 us; speedup 1.0000x reference)
//
#include <hip/hip_runtime.h>
#include <hip/hip_bf16.h>

typedef __attribute__((ext_vector_type(8))) short short8;
typedef __attribute__((ext_vector_type(4))) short short4v;
typedef __attribute__((ext_vector_type(4))) float f32x4;

constexpr int Bb = 8, NN = 2048, FIN = 512, FOUT = 256;
#define LRALPHA 0.2f
#define MFMA16(a, b, c) __builtin_amdgcn_mfma_f32_16x16x32_bf16((a), (b), (c), 0, 0, 0)

static __device__ __forceinline__ ushort f2bf(float f) {
    unsigned u = __float_as_uint(f);
    u += 0x7fffu + ((u >> 16) & 1u);
    return (ushort)(u >> 16);
}
static __device__ __forceinline__ float bf2f(ushort b) { return __uint_as_float(((unsigned)b) << 16); }

// LDS-only barrier: waits ds ops but leaves global loads (vmcnt) in flight.
#define LDSBAR() do { asm volatile("s_waitcnt lgkmcnt(0)" ::: "memory"); \
                      __builtin_amdgcn_s_barrier(); \
                      asm volatile("" ::: "memory"); } while (0)
#define BARONLY() do { asm volatile("" ::: "memory"); \
                       __builtin_amdgcn_s_barrier(); \
                       asm volatile("" ::: "memory"); } while (0)

// ---------------------------------------------------------------------------
// K0: prep. Block k: W row k -> WTh/WTl [n][k] bf16 hi/lo; wa1/wa2[k] = W[k,:]·a.
// ---------------------------------------------------------------------------
__global__ __launch_bounds__(256) void prep(const float* __restrict__ W,
                                            const float* __restrict__ a,
                                            ushort* __restrict__ WTh,
                                            ushort* __restrict__ WTl,
                                            float* __restrict__ wa1,
                                            float* __restrict__ wa2) {
    __shared__ float r1[4], r2[4];
    const int k = blockIdx.x, n = threadIdx.x;
    const int lane = n & 63, wv = n >> 6;
    const float w = W[(size_t)k * FOUT + n];
    const ushort hi = f2bf(w);
    WTh[(size_t)n * FIN + k] = hi;
    WTl[(size_t)n * FIN + k] = f2bf(w - bf2f(hi));
    float p1 = w * a[n], p2 = w * a[FOUT + n];
#pragma unroll
    for (int m = 1; m < 64; m <<= 1) {
        p1 += __shfl_xor(p1, m);
        p2 += __shfl_xor(p2, m);
    }
    if (lane == 0) { r1[wv] = p1; r2[wv] = p2; }
    __syncthreads();
    if (n == 0) {
        wa1[k] = r1[0] + r1[1] + r1[2] + r1[3];
        wa2[k] = r2[0] + r2[1] + r2[2] + r2[3];
    }
}

// ---------------------------------------------------------------------------
// K1: h = x @ W (xh*(Wh+Wl)) + exact fp32 s/t dots + transposed bf16 hT.
// 64m x 128n, BK=64, 512 thr / 8 waves, 2 blocks/CU.
// A-stage COALESCED: thread (row=t>>3, k=(t&7)*8) reads 256B/row bursts,
// converts, ds_write_b128 into fragment-order LDS. x depth-2, B depth-1.
// ---------------------------------------------------------------------------
__global__ __launch_bounds__(512, 4) void gemm_h(const float* __restrict__ x,
                                                 const ushort* __restrict__ WTh,
                                                 const ushort* __restrict__ WTl,
                                                 const float* __restrict__ wa1,
                                                 const float* __restrict__ wa2,
                                                 ushort* __restrict__ hTh,
                                                 float* __restrict__ sv,
                                                 float* __restrict__ tv) {
    __shared__ ushort Ah[4][2][512];     // 8 KB A frags
    __shared__ ushort Tr[8][16][72];     // 18.4 KB transpose buffer

    const int t = threadIdx.x, lane = t & 63, w = t >> 6;
    const int m0 = (blockIdx.x >> 1) * 64;
    const int n0 = (blockIdx.x & 1) * 128;

    // A-stage mapping (coalesced): local row lr, k-offset c8
    const int lr = t >> 3, c8 = (t & 7) * 8;
    const int aif = lr >> 4, akstep = c8 >> 5, ak8 = (c8 >> 3) & 3;
    ushort* adst = &Ah[aif][akstep][(((ak8 << 4) | (lr & 15))) * 8];
    const float* xp = x + (size_t)(m0 + lr) * FIN + c8;

    // B direct-reg frag addresses
    const size_t boff = (size_t)(n0 + w * 16 + (lane & 15)) * FIN + (lane >> 4) * 8;
    const ushort* bph = WTh + boff;
    const ushort* bpl = WTl + boff;

    f32x4 acc[4];
#pragma unroll
    for (int f = 0; f < 4; ++f) acc[f] = (f32x4){0.f, 0.f, 0.f, 0.f};
    float sp = 0.f, tp = 0.f;

    // prologue: x(0), x(1), B(0)
    float4 xa0 = *(const float4*)(xp + 0),  xa1 = *(const float4*)(xp + 4);
    float4 xb0 = *(const float4*)(xp + 64), xb1 = *(const float4*)(xp + 68);
    float4 xc0, xc1, xd0, xd1;
    short8 bhA0 = *(const short8*)(bph + 0),  blA0 = *(const short8*)(bpl + 0);
    short8 bhA1 = *(const short8*)(bph + 32), blA1 = *(const short8*)(bpl + 32);
    short8 bhB0, blB0, bhB1, blB1;

    auto phase = [&](int kt, const float4& c0, const float4& c1, float4& nx0, float4& nx1,
                     const short8& cbh0, const short8& cbl0, const short8& cbh1, const short8& cbl1,
                     short8& nbh0, short8& nbl0, short8& nbh1, short8& nbl1) {
        const int k0 = kt * 64;
        const float fv[8] = {c0.x, c0.y, c0.z, c0.w, c1.x, c1.y, c1.z, c1.w};
        short8 vh;
#pragma unroll
        for (int e = 0; e < 8; ++e) vh[e] = (short)f2bf(fv[e]);
        // exact s/t partials: x . wa  (thread's 8 k-columns this phase)
        const float4 w1a = *(const float4*)(wa1 + k0 + c8);
        const float4 w1b = *(const float4*)(wa1 + k0 + c8 + 4);
        const float4 w2a = *(const float4*)(wa2 + k0 + c8);
        const float4 w2b = *(const float4*)(wa2 + k0 + c8 + 4);
        sp += fv[0]*w1a.x + fv[1]*w1a.y + fv[2]*w1a.z + fv[3]*w1a.w
            + fv[4]*w1b.x + fv[5]*w1b.y + fv[6]*w1b.z + fv[7]*w1b.w;
        tp += fv[0]*w2a.x + fv[1]*w2a.y + fv[2]*w2a.z + fv[3]*w2a.w
            + fv[4]*w2b.x + fv[5]*w2b.y + fv[6]*w2b.z + fv[7]*w2b.w;
        BARONLY();                              // WAR: prev A reads done
        *(short8*)adst = vh;
        LDSBAR();                               // A(kt) visible, vmcnt untouched
        // prefetch x(kt+2), B(kt+1)
        const int kx = (kt + 2 < 8 ? kt + 2 : 7) * 64;
        nx0 = *(const float4*)(xp + kx);
        nx1 = *(const float4*)(xp + kx + 4);
        const int kb = (kt + 1 < 8 ? kt + 1 : 7) * 64;
        nbh0 = *(const short8*)(bph + kb);
        nbl0 = *(const short8*)(bpl + kb);
        nbh1 = *(const short8*)(bph + kb + 32);
        nbl1 = *(const short8*)(bpl + kb + 32);
#pragma unroll
        for (int f = 0; f < 4; ++f) {
            const short8 a0 = *(const short8*)&Ah[f][0][lane * 8];
            const short8 a1 = *(const short8*)&Ah[f][1][lane * 8];
            acc[f] = MFMA16(a0, cbh0, acc[f]);
            acc[f] = MFMA16(a0, cbl0, acc[f]);
            acc[f] = MFMA16(a1, cbh1, acc[f]);
            acc[f] = MFMA16(a1, cbl1, acc[f]);
        }
    };

    for (int kt = 0; kt < 8; kt += 4) {
        phase(kt + 0, xa0, xa1, xc0, xc1, bhA0, blA0, bhA1, blA1, bhB0, blB0, bhB1, blB1);
        phase(kt + 1, xb0, xb1, xd0, xd1, bhB0, blB0, bhB1, blB1, bhA0, blA0, bhA1, blA1);
        phase(kt + 2, xc0, xc1, xa0, xa1, bhA0, blA0, bhA1, blA1, bhB0, blB0, bhB1, blB1);
        phase(kt + 3, xd0, xd1, xb0, xb1, bhB0, blB0, bhB1, blB1, bhA0, blA0, bhA1, blA1);
    }

    // ---- s/t reduce: 8 partials per row live in 8 consecutive lanes ----
    sp += __shfl_xor(sp, 1, 8); sp += __shfl_xor(sp, 2, 8); sp += __shfl_xor(sp, 4, 8);
    tp += __shfl_xor(tp, 1, 8); tp += __shfl_xor(tp, 2, 8); tp += __shfl_xor(tp, 4, 8);
    if ((t & 7) == 0 && n0 == 0) {
        sv[m0 + lr] = sp;
        tv[m0 + lr] = tp;
    }

    // ---- transposed bf16 write via LDS ----
    const int rb = (lane >> 4) * 4;
#pragma unroll
    for (int f = 0; f < 4; ++f)
#pragma unroll
        for (int r = 0; r < 4; ++r)
            Tr[w][lane & 15][f * 16 + rb + r] = f2bf(acc[f][r]);
    __syncthreads();
    const int c = lane >> 2, rowb = (lane & 3) * 16;
    const ushort* src = &Tr[w][c][rowb];
    const short8 v0 = *(const short8*)src;
    const short8 v1 = *(const short8*)(src + 8);
    ushort* dst = hTh + ((size_t)(m0 >> 11) * FOUT + n0 + w * 16 + c) * NN + (m0 & 2047) + rowb;
    *(short8*)dst = v0;
    *(short8*)(dst + 8) = v1;
}

// ---------------------------------------------------------------------------
// K2: fused masked softmax + P@H (MFMA) + elu.
// 32 i-rows/block, b = blockIdx&7 (XCD L2 affinity for hT[b]). 512 thr/8 waves.
// adj reads COALESCED: thread (row=t>>4, j=(t&15)*4) -> 256B/row bursts,
// depth-2 register rotation; H depth-1 ping-pong; P dbuf LDS, 1 barrier/phase.
// ---------------------------------------------------------------------------
__global__ __launch_bounds__(512, 4) void gat_fused(const int* __restrict__ adj,
                                                    const ushort* __restrict__ hTh,
                                                    const float* __restrict__ sv,
                                                    const float* __restrict__ tv,
                                                    float* __restrict__ out) {
    __shared__ float t_l[NN];             // 8 KB
    __shared__ ushort Pf[2][2][2][512];   // 8 KB [buf][ifrag][kstep][lane*8]
    __shared__ float den_l[32];

    const int t = threadIdx.x, lane = t & 63, w = t >> 6;
    const int b = blockIdx.x & 7, i0 = (blockIdx.x >> 3) * 32;

    *(float4*)&t_l[t * 4] = *(const float4*)&tv[b * NN + t * 4];

    // weight-compute mapping (coalesced adj): row r, j-offset jn
    const int r = t >> 4, jn = (t & 15) * 4;
    const float s_i = sv[b * NN + i0 + r];
    const int* adjp = adj + ((size_t)b * NN + i0 + r) * NN + jn;
    const int pif = r >> 4, pkstep = jn >> 5, pk8 = (jn >> 3) & 3;
    const int poff = (((pk8 << 4) | (r & 15))) * 8 + (jn & 4);
    ushort* pdst0 = &Pf[0][pif][pkstep][poff];
    ushort* pdst1 = &Pf[1][pif][pkstep][poff];

    // H fragment base addresses (wave w owns cfrags 2w, 2w+1)
    const ushort* hb = hTh + (size_t)b * FOUT * NN;
    const ushort* h00 = hb + (size_t)(2 * w * 16 + (lane & 15)) * NN + (lane >> 4) * 8;
    const ushort* h10 = hb + (size_t)((2 * w + 1) * 16 + (lane & 15)) * NN + (lane >> 4) * 8;

    f32x4 acc00 = {0.f,0.f,0.f,0.f}, acc01 = acc00, acc10 = acc00, acc11 = acc00;
    float den_part = 0.f;

    // prologue: adj tiles 0,1; H tile 0
    int4 ajA = *(const int4*)(adjp);
    int4 ajB = *(const int4*)(adjp + 64);
    int4 ajC, ajD;
    short8 X00 = *(const short8*)h00, X01 = *(const short8*)(h00 + 32);
    short8 X10 = *(const short8*)h10, X11 = *(const short8*)(h10 + 32);
    short8 Y00, Y01, Y10, Y11;

    __syncthreads();   // t_l ready

    auto phase = [&](int jt, ushort* pdst, int rbuf,
                     const int4& ajcur, int4& aj2,
                     const short8& c00, const short8& c01, const short8& c10, const short8& c11,
                     short8& n00, short8& n01, short8& n10, short8& n11) {
        const int j0 = jt * 64;
        const int jH = min(j0 + 64, NN - 64);    // H prefetch t+1
        const int jA = min(j0 + 128, NN - 64);   // adj prefetch t+2
        n00 = *(const short8*)(h00 + jH);
        n01 = *(const short8*)(h00 + jH + 32);
        n10 = *(const short8*)(h10 + jH);
        n11 = *(const short8*)(h10 + jH + 32);
        aj2 = *(const int4*)(adjp + jA);
        const float4 tq = *(const float4*)&t_l[j0 + jn];
        const float tvv[4] = {tq.x, tq.y, tq.z, tq.w};
        const int avs[4] = {ajcur.x, ajcur.y, ajcur.z, ajcur.w};
        short4v pv;
#pragma unroll
        for (int e = 0; e < 4; ++e) {
            float v = s_i + tvv[e];
            v = v > 0.f ? v : LRALPHA * v;
            const float wv = avs[e] > 0 ? __expf(v) : 0.f;
            const ushort hbv = f2bf(wv);
            den_part += bf2f(hbv);
            pv[e] = (short)hbv;
        }
        *(short4v*)pdst = pv;
        LDSBAR();   // P(t) visible; in-flight global prefetches NOT drained
        const ushort* pr = &Pf[rbuf][0][0][0] + lane * 8;
        const short8 a00 = *(const short8*)(pr);
        const short8 a01 = *(const short8*)(pr + 512);
        const short8 a10 = *(const short8*)(pr + 1024);
        const short8 a11 = *(const short8*)(pr + 1536);
        __builtin_amdgcn_s_setprio(1);
        acc00 = MFMA16(a00, c00, acc00);
        acc00 = MFMA16(a01, c01, acc00);
        acc01 = MFMA16(a00, c10, acc01);
        acc01 = MFMA16(a01, c11, acc01);
        acc10 = MFMA16(a10, c00, acc10);
        acc10 = MFMA16(a11, c01, acc10);
        acc11 = MFMA16(a10, c10, acc11);
        acc11 = MFMA16(a11, c11, acc11);
        __builtin_amdgcn_s_setprio(0);
    };

    for (int tt = 0; tt < NN / 64; tt += 4) {
        phase(tt + 0, pdst0, 0, ajA, ajC, X00, X01, X10, X11, Y00, Y01, Y10, Y11);
        phase(tt + 1, pdst1, 1, ajB, ajD, Y00, Y01, Y10, Y11, X00, X01, X10, X11);
        phase(tt + 2, pdst0, 0, ajC, ajA, X00, X01, X10, X11, Y00, Y01, Y10, Y11);
        phase(tt + 3, pdst1, 1, ajD, ajB, Y00, Y01, Y10, Y11, X00, X01, X10, X11);
    }

    // ---- denominator: 16 j-slice partials per row live in 16 consecutive lanes ----
    den_part += __shfl_xor(den_part, 1, 16);
    den_part += __shfl_xor(den_part, 2, 16);
    den_part += __shfl_xor(den_part, 4, 16);
    den_part += __shfl_xor(den_part, 8, 16);
    if ((t & 15) == 0) den_l[r] = den_part;
    __syncthreads();

    // ---- epilogue: normalize + elu + store ----
    const int rb = (lane >> 4) * 4;
    const f32x4 av[2][2] = {{acc00, acc01}, {acc10, acc11}};
#pragma unroll
    for (int f = 0; f < 2; ++f) {
#pragma unroll
        for (int rr = 0; rr < 4; ++rr) {
            const int row = f * 16 + rb + rr;
            const float inv = 1.0f / den_l[row];
#pragma unroll
            for (int cf = 0; cf < 2; ++cf) {
                float v = av[f][cf][rr] * inv;
                v = v > 0.f ? v : expm1f(v);
                out[((size_t)b * NN + i0 + row) * FOUT + w * 32 + cf * 16 + (lane & 15)] = v;
            }
        }
    }
}

// ---------------------------------------------------------------------------
extern "C" void kernel_launch(void* const* d_in, const int* in_sizes, int n_in,
                              void* d_out, int out_size, void* d_ws, size_t ws_size,
                              hipStream_t stream) {
    const float* x   = (const float*)d_in[0];
    const int*   adj = (const int*)d_in[1];
    const float* W   = (const float*)d_in[2];
    const float* a   = (const float*)d_in[3];
    float* out = (float*)d_out;

    ushort* hTh = (ushort*)d_ws;
    float*  sv  = (float*)(hTh + (size_t)Bb * FOUT * NN);
    float*  tv  = sv + Bb * NN;
    ushort* WTh = (ushort*)(tv + Bb * NN);
    ushort* WTl = WTh + (size_t)FIN * FOUT;
    float*  wa1 = (float*)(WTl + (size_t)FIN * FOUT);
    float*  wa2 = wa1 + FIN;

    prep<<<FIN, 256, 0, stream>>>(W, a, WTh, WTl, wa1, wa2);
    gemm_h<<<512, 512, 0, stream>>>(x, WTh, WTl, wa1, wa2, hTh, sv, tv);
    gat_fused<<<512, 512, 0, stream>>>(adj, hTh, sv, tv, out);
}

// Round 7
// 270.470 us; speedup vs baseline: 1.1233x; 1.1233x over previous
//
#include <hip/hip_runtime.h>
#include <hip/hip_bf16.h>

typedef __attribute__((ext_vector_type(8))) short short8;
typedef __attribute__((ext_vector_type(4))) short short4v;
typedef __attribute__((ext_vector_type(4))) float f32x4;

constexpr int Bb = 8, NN = 2048, FIN = 512, FOUT = 256;
#define LRALPHA 0.2f
#define MFMA16(a, b, c) __builtin_amdgcn_mfma_f32_16x16x32_bf16((a), (b), (c), 0, 0, 0)

static __device__ __forceinline__ ushort f2bf(float f) {
    unsigned u = __float_as_uint(f);
    u += 0x7fffu + ((u >> 16) & 1u);
    return (ushort)(u >> 16);
}
static __device__ __forceinline__ float bf2f(ushort b) { return __uint_as_float(((unsigned)b) << 16); }

// LDS-only barrier: waits ds ops but leaves global loads (vmcnt) in flight.
#define LDSBAR() do { asm volatile("s_waitcnt lgkmcnt(0)" ::: "memory"); \
                      __builtin_amdgcn_s_barrier(); \
                      asm volatile("" ::: "memory"); } while (0)
#define BARONLY() do { asm volatile("" ::: "memory"); \
                       __builtin_amdgcn_s_barrier(); \
                       asm volatile("" ::: "memory"); } while (0)

// ---------------------------------------------------------------------------
// K0: prep. Block k: W row k -> WTh/WTl [n][k] bf16 hi/lo; wa1/wa2[k] = W[k,:]·a.
// ---------------------------------------------------------------------------
__global__ __launch_bounds__(256) void prep(const float* __restrict__ W,
                                            const float* __restrict__ a,
                                            ushort* __restrict__ WTh,
                                            ushort* __restrict__ WTl,
                                            float* __restrict__ wa1,
                                            float* __restrict__ wa2) {
    __shared__ float r1[4], r2[4];
    const int k = blockIdx.x, n = threadIdx.x;
    const int lane = n & 63, wv = n >> 6;
    const float w = W[(size_t)k * FOUT + n];
    const ushort hi = f2bf(w);
    WTh[(size_t)n * FIN + k] = hi;
    WTl[(size_t)n * FIN + k] = f2bf(w - bf2f(hi));
    float p1 = w * a[n], p2 = w * a[FOUT + n];
#pragma unroll
    for (int m = 1; m < 64; m <<= 1) {
        p1 += __shfl_xor(p1, m);
        p2 += __shfl_xor(p2, m);
    }
    if (lane == 0) { r1[wv] = p1; r2[wv] = p2; }
    __syncthreads();
    if (n == 0) {
        wa1[k] = r1[0] + r1[1] + r1[2] + r1[3];
        wa2[k] = r2[0] + r2[1] + r2[2] + r2[3];
    }
}

// ---------------------------------------------------------------------------
// K1: h = x @ W (xh*(Wh+Wl)) + exact fp32 s/t dots + transposed bf16 hT.
// (unchanged from round 5)
// ---------------------------------------------------------------------------
__global__ __launch_bounds__(512, 4) void gemm_h(const float* __restrict__ x,
                                                 const ushort* __restrict__ WTh,
                                                 const ushort* __restrict__ WTl,
                                                 const float* __restrict__ wa1,
                                                 const float* __restrict__ wa2,
                                                 ushort* __restrict__ hTh,
                                                 float* __restrict__ sv,
                                                 float* __restrict__ tv) {
    __shared__ ushort Ah[4][2][512];     // 8 KB A frags
    __shared__ ushort Tr[8][16][72];     // 18.4 KB transpose buffer

    const int t = threadIdx.x, lane = t & 63, w = t >> 6;
    const int m0 = (blockIdx.x >> 1) * 64;
    const int n0 = (blockIdx.x & 1) * 128;

    const int lr = t >> 3, c8 = (t & 7) * 8;
    const int aif = lr >> 4, akstep = c8 >> 5, ak8 = (c8 >> 3) & 3;
    ushort* adst = &Ah[aif][akstep][(((ak8 << 4) | (lr & 15))) * 8];
    const float* xp = x + (size_t)(m0 + lr) * FIN + c8;

    const size_t boff = (size_t)(n0 + w * 16 + (lane & 15)) * FIN + (lane >> 4) * 8;
    const ushort* bph = WTh + boff;
    const ushort* bpl = WTl + boff;

    f32x4 acc[4];
#pragma unroll
    for (int f = 0; f < 4; ++f) acc[f] = (f32x4){0.f, 0.f, 0.f, 0.f};
    float sp = 0.f, tp = 0.f;

    float4 xa0 = *(const float4*)(xp + 0),  xa1 = *(const float4*)(xp + 4);
    float4 xb0 = *(const float4*)(xp + 64), xb1 = *(const float4*)(xp + 68);
    float4 xc0, xc1, xd0, xd1;
    short8 bhA0 = *(const short8*)(bph + 0),  blA0 = *(const short8*)(bpl + 0);
    short8 bhA1 = *(const short8*)(bph + 32), blA1 = *(const short8*)(bpl + 32);
    short8 bhB0, blB0, bhB1, blB1;

    auto phase = [&](int kt, const float4& c0, const float4& c1, float4& nx0, float4& nx1,
                     const short8& cbh0, const short8& cbl0, const short8& cbh1, const short8& cbl1,
                     short8& nbh0, short8& nbl0, short8& nbh1, short8& nbl1) {
        const int k0 = kt * 64;
        const float fv[8] = {c0.x, c0.y, c0.z, c0.w, c1.x, c1.y, c1.z, c1.w};
        short8 vh;
#pragma unroll
        for (int e = 0; e < 8; ++e) vh[e] = (short)f2bf(fv[e]);
        const float4 w1a = *(const float4*)(wa1 + k0 + c8);
        const float4 w1b = *(const float4*)(wa1 + k0 + c8 + 4);
        const float4 w2a = *(const float4*)(wa2 + k0 + c8);
        const float4 w2b = *(const float4*)(wa2 + k0 + c8 + 4);
        sp += fv[0]*w1a.x + fv[1]*w1a.y + fv[2]*w1a.z + fv[3]*w1a.w
            + fv[4]*w1b.x + fv[5]*w1b.y + fv[6]*w1b.z + fv[7]*w1b.w;
        tp += fv[0]*w2a.x + fv[1]*w2a.y + fv[2]*w2a.z + fv[3]*w2a.w
            + fv[4]*w2b.x + fv[5]*w2b.y + fv[6]*w2b.z + fv[7]*w2b.w;
        BARONLY();
        *(short8*)adst = vh;
        LDSBAR();
        const int kx = (kt + 2 < 8 ? kt + 2 : 7) * 64;
        nx0 = *(const float4*)(xp + kx);
        nx1 = *(const float4*)(xp + kx + 4);
        const int kb = (kt + 1 < 8 ? kt + 1 : 7) * 64;
        nbh0 = *(const short8*)(bph + kb);
        nbl0 = *(const short8*)(bpl + kb);
        nbh1 = *(const short8*)(bph + kb + 32);
        nbl1 = *(const short8*)(bpl + kb + 32);
#pragma unroll
        for (int f = 0; f < 4; ++f) {
            const short8 a0 = *(const short8*)&Ah[f][0][lane * 8];
            const short8 a1 = *(const short8*)&Ah[f][1][lane * 8];
            acc[f] = MFMA16(a0, cbh0, acc[f]);
            acc[f] = MFMA16(a0, cbl0, acc[f]);
            acc[f] = MFMA16(a1, cbh1, acc[f]);
            acc[f] = MFMA16(a1, cbl1, acc[f]);
        }
    };

    for (int kt = 0; kt < 8; kt += 4) {
        phase(kt + 0, xa0, xa1, xc0, xc1, bhA0, blA0, bhA1, blA1, bhB0, blB0, bhB1, blB1);
        phase(kt + 1, xb0, xb1, xd0, xd1, bhB0, blB0, bhB1, blB1, bhA0, blA0, bhA1, blA1);
        phase(kt + 2, xc0, xc1, xa0, xa1, bhA0, blA0, bhA1, blA1, bhB0, blB0, bhB1, blB1);
        phase(kt + 3, xd0, xd1, xb0, xb1, bhB0, blB0, bhB1, blB1, bhA0, blA0, bhA1, blA1);
    }

    sp += __shfl_xor(sp, 1, 8); sp += __shfl_xor(sp, 2, 8); sp += __shfl_xor(sp, 4, 8);
    tp += __shfl_xor(tp, 1, 8); tp += __shfl_xor(tp, 2, 8); tp += __shfl_xor(tp, 4, 8);
    if ((t & 7) == 0 && n0 == 0) {
        sv[m0 + lr] = sp;
        tv[m0 + lr] = tp;
    }

    const int rb = (lane >> 4) * 4;
#pragma unroll
    for (int f = 0; f < 4; ++f)
#pragma unroll
        for (int r = 0; r < 4; ++r)
            Tr[w][lane & 15][f * 16 + rb + r] = f2bf(acc[f][r]);
    __syncthreads();
    const int c = lane >> 2, rowb = (lane & 3) * 16;
    const ushort* src = &Tr[w][c][rowb];
    const short8 v0 = *(const short8*)src;
    const short8 v1 = *(const short8*)(src + 8);
    ushort* dst = hTh + ((size_t)(m0 >> 11) * FOUT + n0 + w * 16 + c) * NN + (m0 & 2047) + rowb;
    *(short8*)dst = v0;
    *(short8*)(dst + 8) = v1;
}

// ---------------------------------------------------------------------------
// K2: fused masked softmax + P@H (MFMA) + elu.
// 64 i-rows/block (halves H re-read: 256 blocks x 1 MB), b = blockIdx&7
// (XCD affinity). 512 thr / 8 waves, grid 256.
// Per 64-j phase: thread owns (row r = t>>3, 8 j's at jn=(t&7)*8) -> 256B/row
// coalesced adj; 8 weights -> P frags (4 ifrag x 2 kstep, dbuf, 1 LDSBAR);
// wave w multiplies all 4 ifrags with its 2 cfrags: 16 MFMAs/phase.
// adj depth-2 register rotation; H depth-1 ping-pong; vmcnt never drained.
// Pf strides: ifrag = 1024 elems, kstep = 512 elems (bug fixed from R6).
// ---------------------------------------------------------------------------
__global__ __launch_bounds__(512, 2) void gat_fused(const int* __restrict__ adj,
                                                    const ushort* __restrict__ hTh,
                                                    const float* __restrict__ sv,
                                                    const float* __restrict__ tv,
                                                    float* __restrict__ out) {
    __shared__ float t_l[NN];             // 8 KB
    __shared__ ushort Pf[2][4][2][512];   // 16 KB [buf][ifrag][kstep][lane*8]
    __shared__ float den_l[64];

    const int t = threadIdx.x, lane = t & 63, w = t >> 6;
    const int b = blockIdx.x & 7, i0 = (blockIdx.x >> 3) * 64;

    *(float4*)&t_l[t * 4] = *(const float4*)&tv[b * NN + t * 4];

    // weight-compute mapping: row r (8 threads/row), 8 j's at jn
    const int r = t >> 3, jn = (t & 7) * 8;
    const float s_i = sv[b * NN + i0 + r];
    const int* adjp = adj + ((size_t)b * NN + i0 + r) * NN + jn;
    const int pif = r >> 4, pkstep = jn >> 5, pk8 = (jn >> 3) & 3;
    ushort* pdst0 = &Pf[0][pif][pkstep][((pk8 << 4) | (r & 15)) * 8];
    ushort* pdst1 = &Pf[1][pif][pkstep][((pk8 << 4) | (r & 15)) * 8];

    // H fragment bases (wave w owns cfrags 2w, 2w+1)
    const ushort* hb = hTh + (size_t)b * FOUT * NN;
    const ushort* h00 = hb + (size_t)(2 * w * 16 + (lane & 15)) * NN + (lane >> 4) * 8;
    const ushort* h10 = hb + (size_t)((2 * w + 1) * 16 + (lane & 15)) * NN + (lane >> 4) * 8;

    f32x4 acc[4][2];
#pragma unroll
    for (int f = 0; f < 4; ++f) {
        acc[f][0] = (f32x4){0.f, 0.f, 0.f, 0.f};
        acc[f][1] = (f32x4){0.f, 0.f, 0.f, 0.f};
    }
    float den_part = 0.f;

    // prologue: adj tiles 0,1 (2 int4 each); H tile 0
    int4 ajA0 = *(const int4*)(adjp),      ajA1 = *(const int4*)(adjp + 4);
    int4 ajB0 = *(const int4*)(adjp + 64), ajB1 = *(const int4*)(adjp + 68);
    int4 ajC0, ajC1, ajD0, ajD1;
    short8 X00 = *(const short8*)h00, X01 = *(const short8*)(h00 + 32);
    short8 X10 = *(const short8*)h10, X11 = *(const short8*)(h10 + 32);
    short8 Y00, Y01, Y10, Y11;

    __syncthreads();   // t_l ready (one-time)

    auto phase = [&](int jt, ushort* pdst, int rbuf,
                     const int4& ac0, const int4& ac1, int4& an0, int4& an1,
                     const short8& c00, const short8& c01, const short8& c10, const short8& c11,
                     short8& n00, short8& n01, short8& n10, short8& n11) {
        const int j0 = jt * 64;
        const int jH = min(j0 + 64, NN - 64);    // H prefetch t+1
        const int jA = min(j0 + 128, NN - 64);   // adj prefetch t+2
        n00 = *(const short8*)(h00 + jH);
        n01 = *(const short8*)(h00 + jH + 32);
        n10 = *(const short8*)(h10 + jH);
        n11 = *(const short8*)(h10 + jH + 32);
        an0 = *(const int4*)(adjp + jA);
        an1 = *(const int4*)(adjp + jA + 4);
        // 8 weights for (row r, j = j0+jn .. +7)
        const float4 tq0 = *(const float4*)&t_l[j0 + jn];
        const float4 tq1 = *(const float4*)&t_l[j0 + jn + 4];
        const float tvv[8] = {tq0.x, tq0.y, tq0.z, tq0.w, tq1.x, tq1.y, tq1.z, tq1.w};
        const int avs[8] = {ac0.x, ac0.y, ac0.z, ac0.w, ac1.x, ac1.y, ac1.z, ac1.w};
        short8 pv;
#pragma unroll
        for (int e = 0; e < 8; ++e) {
            float v = s_i + tvv[e];
            v = v > 0.f ? v : LRALPHA * v;
            const float wv = avs[e] > 0 ? __expf(v) : 0.f;
            const ushort hbv = f2bf(wv);
            den_part += bf2f(hbv);
            pv[e] = (short)hbv;
        }
        *(short8*)pdst = pv;
        LDSBAR();   // P(t) visible; global prefetches stay in flight
        const ushort* pr = &Pf[rbuf][0][0][0] + lane * 8;
        __builtin_amdgcn_s_setprio(1);
#pragma unroll
        for (int f = 0; f < 4; ++f) {
            const short8 a0 = *(const short8*)(pr + f * 1024);
            const short8 a1 = *(const short8*)(pr + f * 1024 + 512);
            acc[f][0] = MFMA16(a0, c00, acc[f][0]);
            acc[f][0] = MFMA16(a1, c01, acc[f][0]);
            acc[f][1] = MFMA16(a0, c10, acc[f][1]);
            acc[f][1] = MFMA16(a1, c11, acc[f][1]);
        }
        __builtin_amdgcn_s_setprio(0);
    };

    for (int tt = 0; tt < NN / 64; tt += 4) {
        phase(tt + 0, pdst0, 0, ajA0, ajA1, ajC0, ajC1, X00, X01, X10, X11, Y00, Y01, Y10, Y11);
        phase(tt + 1, pdst1, 1, ajB0, ajB1, ajD0, ajD1, Y00, Y01, Y10, Y11, X00, X01, X10, X11);
        phase(tt + 2, pdst0, 0, ajC0, ajC1, ajA0, ajA1, X00, X01, X10, X11, Y00, Y01, Y10, Y11);
        phase(tt + 3, pdst1, 1, ajD0, ajD1, ajB0, ajB1, Y00, Y01, Y10, Y11, X00, X01, X10, X11);
    }

    // ---- denominator: 8 j-slice partials per row in 8 consecutive lanes ----
    den_part += __shfl_xor(den_part, 1, 8);
    den_part += __shfl_xor(den_part, 2, 8);
    den_part += __shfl_xor(den_part, 4, 8);
    if ((t & 7) == 0) den_l[r] = den_part;
    __syncthreads();

    // ---- epilogue: normalize + elu + store ----
    const int rb = (lane >> 4) * 4;
#pragma unroll
    for (int f = 0; f < 4; ++f) {
#pragma unroll
        for (int rr = 0; rr < 4; ++rr) {
            const int row = f * 16 + rb + rr;
            const float inv = 1.0f / den_l[row];
#pragma unroll
            for (int cf = 0; cf < 2; ++cf) {
                float v = acc[f][cf][rr] * inv;
                v = v > 0.f ? v : expm1f(v);
                out[((size_t)b * NN + i0 + row) * FOUT + w * 32 + cf * 16 + (lane & 15)] = v;
            }
        }
    }
}

// ---------------------------------------------------------------------------
extern "C" void kernel_launch(void* const* d_in, const int* in_sizes, int n_in,
                              void* d_out, int out_size, void* d_ws, size_t ws_size,
                              hipStream_t stream) {
    const float* x   = (const float*)d_in[0];
    const int*   adj = (const int*)d_in[1];
    const float* W   = (const float*)d_in[2];
    const float* a   = (const float*)d_in[3];
    float* out = (float*)d_out;

    ushort* hTh = (ushort*)d_ws;
    float*  sv  = (float*)(hTh + (size_t)Bb * FOUT * NN);
    float*  tv  = sv + Bb * NN;
    ushort* WTh = (ushort*)(tv + Bb * NN);
    ushort* WTl = WTh + (size_t)FIN * FOUT;
    float*  wa1 = (float*)(WTl + (size_t)FIN * FOUT);
    float*  wa2 = wa1 + FIN;

    prep<<<FIN, 256, 0, stream>>>(W, a, WTh, WTl, wa1, wa2);
    gemm_h<<<512, 512, 0, stream>>>(x, WTh, WTl, wa1, wa2, hTh, sv, tv);
    gat_fused<<<256, 512, 0, stream>>>(adj, hTh, sv, tv, out);
}

// Round 8
// 261.880 us; speedup vs baseline: 1.1601x; 1.0328x over previous
//
#include <hip/hip_runtime.h>
#include <hip/hip_bf16.h>

typedef __attribute__((ext_vector_type(8))) short short8;
typedef __attribute__((ext_vector_type(4))) float f32x4;

constexpr int Bb = 8, NN = 2048, FIN = 512, FOUT = 256;
#define LRALPHA 0.2f
#define MFMA16(a, b, c) __builtin_amdgcn_mfma_f32_16x16x32_bf16((a), (b), (c), 0, 0, 0)

static __device__ __forceinline__ ushort f2bf(float f) {
    unsigned u = __float_as_uint(f);
    u += 0x7fffu + ((u >> 16) & 1u);
    return (ushort)(u >> 16);
}
static __device__ __forceinline__ float bf2f(ushort b) { return __uint_as_float(((unsigned)b) << 16); }

// LDS-only barrier: waits ds ops but leaves global loads (vmcnt) in flight.
#define LDSBAR() do { asm volatile("s_waitcnt lgkmcnt(0)" ::: "memory"); \
                      __builtin_amdgcn_s_barrier(); \
                      asm volatile("" ::: "memory"); } while (0)
#define BARONLY() do { asm volatile("" ::: "memory"); \
                       __builtin_amdgcn_s_barrier(); \
                       asm volatile("" ::: "memory"); } while (0)

// ---------------------------------------------------------------------------
// K0: prep. Block k: W row k -> WTh/WTl [n][k] bf16 hi/lo; wa1/wa2[k] = W[k,:]·a.
// ---------------------------------------------------------------------------
__global__ __launch_bounds__(256) void prep(const float* __restrict__ W,
                                            const float* __restrict__ a,
                                            ushort* __restrict__ WTh,
                                            ushort* __restrict__ WTl,
                                            float* __restrict__ wa1,
                                            float* __restrict__ wa2) {
    __shared__ float r1[4], r2[4];
    const int k = blockIdx.x, n = threadIdx.x;
    const int lane = n & 63, wv = n >> 6;
    const float w = W[(size_t)k * FOUT + n];
    const ushort hi = f2bf(w);
    WTh[(size_t)n * FIN + k] = hi;
    WTl[(size_t)n * FIN + k] = f2bf(w - bf2f(hi));
    float p1 = w * a[n], p2 = w * a[FOUT + n];
#pragma unroll
    for (int m = 1; m < 64; m <<= 1) {
        p1 += __shfl_xor(p1, m);
        p2 += __shfl_xor(p2, m);
    }
    if (lane == 0) { r1[wv] = p1; r2[wv] = p2; }
    __syncthreads();
    if (n == 0) {
        wa1[k] = r1[0] + r1[1] + r1[2] + r1[3];
        wa2[k] = r2[0] + r2[1] + r2[2] + r2[3];
    }
}

// ---------------------------------------------------------------------------
// K1: h = x @ W (xh*(Wh+Wl)) + exact fp32 s/t dots + transposed bf16 hT.
// Tile 64m x 256n (FULL output width), grid 256 -> x read ONCE (33.5 MB),
// every block exclusively owns its 64 rows (no s/t guard). 512 thr / 8 waves,
// wave w owns cols [w*32, w*32+32) = cfrags {2w, 2w+1}. 32 MFMAs/phase/wave.
// A staged coalesced->frag-order LDS; B reg ping-pong; raw barriers.
// ---------------------------------------------------------------------------
__global__ __launch_bounds__(512, 2) void gemm_h(const float* __restrict__ x,
                                                 const ushort* __restrict__ WTh,
                                                 const ushort* __restrict__ WTl,
                                                 const float* __restrict__ wa1,
                                                 const float* __restrict__ wa2,
                                                 ushort* __restrict__ hTh,
                                                 float* __restrict__ sv,
                                                 float* __restrict__ tv) {
    __shared__ ushort Ah[4][2][512];     // 8 KB A frags
    __shared__ ushort Tr[8][16][72];     // 18.4 KB transpose buffer (per-wave)

    const int t = threadIdx.x, lane = t & 63, w = t >> 6;
    const int m0 = blockIdx.x * 64;

    // A-stage (coalesced): local row lr, k-offset c8; frag-order LDS dst
    const int lr = t >> 3, c8 = (t & 7) * 8;
    const int aif = lr >> 4, akstep = c8 >> 5, ak8 = (c8 >> 3) & 3;
    ushort* adst = &Ah[aif][akstep][(((ak8 << 4) | (lr & 15))) * 8];
    const float* xp = x + (size_t)(m0 + lr) * FIN + c8;

    // B frag bases: cfrag 2w (cols w*32+..) and 2w+1 (+16 cols)
    const size_t b0 = (size_t)(w * 32 + (lane & 15)) * FIN + (lane >> 4) * 8;
    const size_t b1 = b0 + (size_t)16 * FIN;
    const ushort *ph0 = WTh + b0, *pl0 = WTl + b0;
    const ushort *ph1 = WTh + b1, *pl1 = WTl + b1;

    f32x4 acc[4][2];
#pragma unroll
    for (int f = 0; f < 4; ++f) {
        acc[f][0] = (f32x4){0.f, 0.f, 0.f, 0.f};
        acc[f][1] = (f32x4){0.f, 0.f, 0.f, 0.f};
    }
    float sp = 0.f, tp = 0.f;

    // x prologue depth-2 (period-4 rotation)
    float4 xa0 = *(const float4*)(xp + 0),  xa1 = *(const float4*)(xp + 4);
    float4 xb0 = *(const float4*)(xp + 64), xb1 = *(const float4*)(xp + 68);
    float4 xc0, xc1, xd0, xd1;
    // B prologue (phase 0), ping-pong sets A/B: {cf0: hk0,lk0,hk1,lk1; cf1: ...}
    short8 A00 = *(const short8*)(ph0 + 0),  A01 = *(const short8*)(pl0 + 0);
    short8 A02 = *(const short8*)(ph0 + 32), A03 = *(const short8*)(pl0 + 32);
    short8 A10 = *(const short8*)(ph1 + 0),  A11 = *(const short8*)(pl1 + 0);
    short8 A12 = *(const short8*)(ph1 + 32), A13 = *(const short8*)(pl1 + 32);
    short8 B00, B01, B02, B03, B10, B11, B12, B13;

    auto phase = [&](int kt, const float4& c0, const float4& c1, float4& nx0, float4& nx1,
                     const short8& g00, const short8& g01, const short8& g02, const short8& g03,
                     const short8& g10, const short8& g11, const short8& g12, const short8& g13,
                     short8& n00, short8& n01, short8& n02, short8& n03,
                     short8& n10, short8& n11, short8& n12, short8& n13) {
        const int k0 = kt * 64;
        const float fv[8] = {c0.x, c0.y, c0.z, c0.w, c1.x, c1.y, c1.z, c1.w};
        short8 vh;
#pragma unroll
        for (int e = 0; e < 8; ++e) vh[e] = (short)f2bf(fv[e]);
        // exact s/t partials: x . wa over this phase's 8 k-cols
        const float4 w1a = *(const float4*)(wa1 + k0 + c8);
        const float4 w1b = *(const float4*)(wa1 + k0 + c8 + 4);
        const float4 w2a = *(const float4*)(wa2 + k0 + c8);
        const float4 w2b = *(const float4*)(wa2 + k0 + c8 + 4);
        sp += fv[0]*w1a.x + fv[1]*w1a.y + fv[2]*w1a.z + fv[3]*w1a.w
            + fv[4]*w1b.x + fv[5]*w1b.y + fv[6]*w1b.z + fv[7]*w1b.w;
        tp += fv[0]*w2a.x + fv[1]*w2a.y + fv[2]*w2a.z + fv[3]*w2a.w
            + fv[4]*w2b.x + fv[5]*w2b.y + fv[6]*w2b.z + fv[7]*w2b.w;
        BARONLY();                              // WAR: prev A reads done
        *(short8*)adst = vh;
        LDSBAR();                               // A(kt) visible, vmcnt untouched
        // prefetch x(kt+2), B(kt+1)
        const int kx = (kt + 2 < 8 ? kt + 2 : 7) * 64;
        nx0 = *(const float4*)(xp + kx);
        nx1 = *(const float4*)(xp + kx + 4);
        const int kb = (kt + 1 < 8 ? kt + 1 : 7) * 64;
        n00 = *(const short8*)(ph0 + kb);      n01 = *(const short8*)(pl0 + kb);
        n02 = *(const short8*)(ph0 + kb + 32); n03 = *(const short8*)(pl0 + kb + 32);
        n10 = *(const short8*)(ph1 + kb);      n11 = *(const short8*)(pl1 + kb);
        n12 = *(const short8*)(ph1 + kb + 32); n13 = *(const short8*)(pl1 + kb + 32);
#pragma unroll
        for (int f = 0; f < 4; ++f) {
            const short8 a0 = *(const short8*)&Ah[f][0][lane * 8];
            const short8 a1 = *(const short8*)&Ah[f][1][lane * 8];
            acc[f][0] = MFMA16(a0, g00, acc[f][0]);
            acc[f][0] = MFMA16(a0, g01, acc[f][0]);
            acc[f][0] = MFMA16(a1, g02, acc[f][0]);
            acc[f][0] = MFMA16(a1, g03, acc[f][0]);
            acc[f][1] = MFMA16(a0, g10, acc[f][1]);
            acc[f][1] = MFMA16(a0, g11, acc[f][1]);
            acc[f][1] = MFMA16(a1, g12, acc[f][1]);
            acc[f][1] = MFMA16(a1, g13, acc[f][1]);
        }
    };

    for (int kt = 0; kt < 8; kt += 4) {
        phase(kt + 0, xa0, xa1, xc0, xc1, A00,A01,A02,A03,A10,A11,A12,A13,
                                           B00,B01,B02,B03,B10,B11,B12,B13);
        phase(kt + 1, xb0, xb1, xd0, xd1, B00,B01,B02,B03,B10,B11,B12,B13,
                                           A00,A01,A02,A03,A10,A11,A12,A13);
        phase(kt + 2, xc0, xc1, xa0, xa1, A00,A01,A02,A03,A10,A11,A12,A13,
                                           B00,B01,B02,B03,B10,B11,B12,B13);
        phase(kt + 3, xd0, xd1, xb0, xb1, B00,B01,B02,B03,B10,B11,B12,B13,
                                           A00,A01,A02,A03,A10,A11,A12,A13);
    }

    // ---- s/t reduce: 8 partials per row in 8 consecutive lanes ----
    sp += __shfl_xor(sp, 1, 8); sp += __shfl_xor(sp, 2, 8); sp += __shfl_xor(sp, 4, 8);
    tp += __shfl_xor(tp, 1, 8); tp += __shfl_xor(tp, 2, 8); tp += __shfl_xor(tp, 4, 8);
    if ((t & 7) == 0) {
        sv[m0 + lr] = sp;
        tv[m0 + lr] = tp;
    }

    // ---- transposed bf16 write via per-wave LDS, two passes (cfrag 2w, 2w+1) ----
    const int rb = (lane >> 4) * 4;
    const int c = lane >> 2, rowb = (lane & 3) * 16;
#pragma unroll
    for (int p = 0; p < 2; ++p) {
        __syncthreads();
#pragma unroll
        for (int f = 0; f < 4; ++f)
#pragma unroll
            for (int r = 0; r < 4; ++r)
                Tr[w][lane & 15][f * 16 + rb + r] = f2bf(acc[f][p][r]);
        __syncthreads();
        const ushort* src = &Tr[w][c][rowb];
        const short8 v0 = *(const short8*)src;
        const short8 v1 = *(const short8*)(src + 8);
        ushort* dst = hTh + ((size_t)(m0 >> 11) * FOUT + w * 32 + p * 16 + c) * NN
                      + (m0 & 2047) + rowb;
        *(short8*)dst = v0;
        *(short8*)(dst + 8) = v1;
    }
}

// ---------------------------------------------------------------------------
// K2: fused masked softmax + P@H (MFMA) + elu.
// 64 i-rows/block, b = blockIdx&7 (XCD affinity). 512 thr / 8 waves, grid 256.
// adj: depth-4 consume-then-refill register sets (covers L3/HBM latency);
// H: depth-2 ping-pong, refilled AFTER its MFMAs. P dbuf LDS, 1 LDSBAR/phase;
// vmcnt never drained in the loop.
// ---------------------------------------------------------------------------
__global__ __launch_bounds__(512, 2) void gat_fused(const int* __restrict__ adj,
                                                    const ushort* __restrict__ hTh,
                                                    const float* __restrict__ sv,
                                                    const float* __restrict__ tv,
                                                    float* __restrict__ out) {
    __shared__ float t_l[NN];             // 8 KB
    __shared__ ushort Pf[2][4][2][512];   // 16 KB [buf][ifrag][kstep][lane*8]
    __shared__ float den_l[64];

    const int t = threadIdx.x, lane = t & 63, w = t >> 6;
    const int b = blockIdx.x & 7, i0 = (blockIdx.x >> 3) * 64;

    *(float4*)&t_l[t * 4] = *(const float4*)&tv[b * NN + t * 4];

    // weight-compute mapping: row r (8 threads/row), 8 j's at jn
    const int r = t >> 3, jn = (t & 7) * 8;
    const float s_i = sv[b * NN + i0 + r];
    const int* adjp = adj + ((size_t)b * NN + i0 + r) * NN + jn;
    const int pif = r >> 4, pkstep = jn >> 5, pk8 = (jn >> 3) & 3;
    ushort* pdst0 = &Pf[0][pif][pkstep][((pk8 << 4) | (r & 15)) * 8];
    ushort* pdst1 = &Pf[1][pif][pkstep][((pk8 << 4) | (r & 15)) * 8];

    // H fragment bases (wave w owns cfrags 2w, 2w+1)
    const ushort* hb = hTh + (size_t)b * FOUT * NN;
    const ushort* h00 = hb + (size_t)(2 * w * 16 + (lane & 15)) * NN + (lane >> 4) * 8;
    const ushort* h10 = hb + (size_t)((2 * w + 1) * 16 + (lane & 15)) * NN + (lane >> 4) * 8;

    f32x4 acc[4][2];
#pragma unroll
    for (int f = 0; f < 4; ++f) {
        acc[f][0] = (f32x4){0.f, 0.f, 0.f, 0.f};
        acc[f][1] = (f32x4){0.f, 0.f, 0.f, 0.f};
    }
    float den_part = 0.f;

    // prologue: adj tiles 0..3 (depth-4); H tiles 0,1 (depth-2)
    int4 ajA0 = *(const int4*)(adjp +   0), ajA1 = *(const int4*)(adjp +   4);
    int4 ajB0 = *(const int4*)(adjp +  64), ajB1 = *(const int4*)(adjp +  68);
    int4 ajC0 = *(const int4*)(adjp + 128), ajC1 = *(const int4*)(adjp + 132);
    int4 ajD0 = *(const int4*)(adjp + 192), ajD1 = *(const int4*)(adjp + 196);
    short8 X00 = *(const short8*)h00,        X01 = *(const short8*)(h00 + 32);
    short8 X10 = *(const short8*)h10,        X11 = *(const short8*)(h10 + 32);
    short8 Y00 = *(const short8*)(h00 + 64), Y01 = *(const short8*)(h00 + 96);
    short8 Y10 = *(const short8*)(h10 + 64), Y11 = *(const short8*)(h10 + 96);

    __syncthreads();   // t_l ready (one-time)

    auto phase = [&](int jt, ushort* pdst, int rbuf,
                     int4& as0, int4& as1,
                     short8& H00, short8& H01, short8& H10, short8& H11) {
        const int j0 = jt * 64;
        // consume adj set into locals, refill for jt+4
        const int avs[8] = {as0.x, as0.y, as0.z, as0.w, as1.x, as1.y, as1.z, as1.w};
        const int jA = min(j0 + 256, NN - 64);
        as0 = *(const int4*)(adjp + jA);
        as1 = *(const int4*)(adjp + jA + 4);
        // weights for (row r, j = j0+jn .. +7)
        const float4 tq0 = *(const float4*)&t_l[j0 + jn];
        const float4 tq1 = *(const float4*)&t_l[j0 + jn + 4];
        const float tvv[8] = {tq0.x, tq0.y, tq0.z, tq0.w, tq1.x, tq1.y, tq1.z, tq1.w};
        short8 pv;
#pragma unroll
        for (int e = 0; e < 8; ++e) {
            float v = s_i + tvv[e];
            v = v > 0.f ? v : LRALPHA * v;
            const float wv = avs[e] > 0 ? __expf(v) : 0.f;
            const ushort hbv = f2bf(wv);
            den_part += bf2f(hbv);
            pv[e] = (short)hbv;
        }
        *(short8*)pdst = pv;
        LDSBAR();   // P(jt) visible; global prefetches stay in flight
        const ushort* pr = &Pf[rbuf][0][0][0] + lane * 8;
        __builtin_amdgcn_s_setprio(1);
#pragma unroll
        for (int f = 0; f < 4; ++f) {
            const short8 a0 = *(const short8*)(pr + f * 1024);
            const short8 a1 = *(const short8*)(pr + f * 1024 + 512);
            acc[f][0] = MFMA16(a0, H00, acc[f][0]);
            acc[f][0] = MFMA16(a1, H01, acc[f][0]);
            acc[f][1] = MFMA16(a0, H10, acc[f][1]);
            acc[f][1] = MFMA16(a1, H11, acc[f][1]);
        }
        __builtin_amdgcn_s_setprio(0);
        // refill H set for jt+2 (after its MFMAs consumed the old values)
        const int jH = min(j0 + 128, NN - 64);
        H00 = *(const short8*)(h00 + jH);
        H01 = *(const short8*)(h00 + jH + 32);
        H10 = *(const short8*)(h10 + jH);
        H11 = *(const short8*)(h10 + jH + 32);
    };

    for (int tt = 0; tt < NN / 64; tt += 4) {
        phase(tt + 0, pdst0, 0, ajA0, ajA1, X00, X01, X10, X11);
        phase(tt + 1, pdst1, 1, ajB0, ajB1, Y00, Y01, Y10, Y11);
        phase(tt + 2, pdst0, 0, ajC0, ajC1, X00, X01, X10, X11);
        phase(tt + 3, pdst1, 1, ajD0, ajD1, Y00, Y01, Y10, Y11);
    }

    // ---- denominator: 8 j-slice partials per row in 8 consecutive lanes ----
    den_part += __shfl_xor(den_part, 1, 8);
    den_part += __shfl_xor(den_part, 2, 8);
    den_part += __shfl_xor(den_part, 4, 8);
    if ((t & 7) == 0) den_l[r] = den_part;
    __syncthreads();

    // ---- epilogue: normalize + elu + store ----
    const int rb = (lane >> 4) * 4;
#pragma unroll
    for (int f = 0; f < 4; ++f) {
#pragma unroll
        for (int rr = 0; rr < 4; ++rr) {
            const int row = f * 16 + rb + rr;
            const float inv = 1.0f / den_l[row];
#pragma unroll
            for (int cf = 0; cf < 2; ++cf) {
                float v = acc[f][cf][rr] * inv;
                v = v > 0.f ? v : expm1f(v);
                out[((size_t)b * NN + i0 + row) * FOUT + w * 32 + cf * 16 + (lane & 15)] = v;
            }
        }
    }
}

// ---------------------------------------------------------------------------
extern "C" void kernel_launch(void* const* d_in, const int* in_sizes, int n_in,
                              void* d_out, int out_size, void* d_ws, size_t ws_size,
                              hipStream_t stream) {
    const float* x   = (const float*)d_in[0];
    const int*   adj = (const int*)d_in[1];
    const float* W   = (const float*)d_in[2];
    const float* a   = (const float*)d_in[3];
    float* out = (float*)d_out;

    ushort* hTh = (ushort*)d_ws;
    float*  sv  = (float*)(hTh + (size_t)Bb * FOUT * NN);
    float*  tv  = sv + Bb * NN;
    ushort* WTh = (ushort*)(tv + Bb * NN);
    ushort* WTl = WTh + (size_t)FIN * FOUT;
    float*  wa1 = (float*)(WTl + (size_t)FIN * FOUT);
    float*  wa2 = wa1 + FIN;

    prep<<<FIN, 256, 0, stream>>>(W, a, WTh, WTl, wa1, wa2);
    gemm_h<<<256, 512, 0, stream>>>(x, WTh, WTl, wa1, wa2, hTh, sv, tv);
    gat_fused<<<256, 512, 0, stream>>>(adj, hTh, sv, tv, out);
}